// Round 5
// baseline (920.688 us; speedup 1.0000x reference)
//
#include <hip/hip_runtime.h>
#include <hip/hip_bf16.h>
#include <hip/hip_fp16.h>

typedef _Float16 half8 __attribute__((ext_vector_type(8)));
typedef _Float16 h2    __attribute__((ext_vector_type(2)));
typedef float    f32x4 __attribute__((ext_vector_type(4)));

// ---------------- graph prep ----------------

// deg[col[e]]++ over E edges; cnt[batch[i]]++ over N nodes (merged launch)
__global__ void count2_k(const int* __restrict__ col, unsigned int* __restrict__ deg,
                         const int* __restrict__ batch, unsigned int* __restrict__ cnt,
                         int E, int N) {
    int e = blockIdx.x * blockDim.x + threadIdx.x;
    if (e < E) atomicAdd(&deg[col[e]], 1u);
    if (e < N) atomicAdd(&cnt[batch[e]], 1u);
}

// exclusive scan of deg -> row_ptr partials; also emits dis = rsqrt(deg+1)
__global__ void scan1_k(const unsigned int* __restrict__ deg,
                        int* __restrict__ out, int* __restrict__ bsum,
                        float* __restrict__ dis, int N) {
    __shared__ int lds[256];
    int t = threadIdx.x;
    int base = blockIdx.x * 1024 + t * 4;
    int v0 = (base + 0 < N) ? (int)deg[base + 0] : 0;
    int v1 = (base + 1 < N) ? (int)deg[base + 1] : 0;
    int v2 = (base + 2 < N) ? (int)deg[base + 2] : 0;
    int v3 = (base + 3 < N) ? (int)deg[base + 3] : 0;
    if (base + 0 < N) dis[base + 0] = rsqrtf((float)(v0 + 1));
    if (base + 1 < N) dis[base + 1] = rsqrtf((float)(v1 + 1));
    if (base + 2 < N) dis[base + 2] = rsqrtf((float)(v2 + 1));
    if (base + 3 < N) dis[base + 3] = rsqrtf((float)(v3 + 1));
    lds[t] = v0 + v1 + v2 + v3;
    __syncthreads();
    for (int off = 1; off < 256; off <<= 1) {
        int x = lds[t];
        int y = (t >= off) ? lds[t - off] : 0;
        __syncthreads();
        lds[t] = x + y;
        __syncthreads();
    }
    int excl = (t == 0) ? 0 : lds[t - 1];
    if (base + 0 < N) out[base + 0] = excl;
    excl += v0;
    if (base + 1 < N) out[base + 1] = excl;
    excl += v1;
    if (base + 2 < N) out[base + 2] = excl;
    excl += v2;
    if (base + 3 < N) out[base + 3] = excl;
    if (t == 255) bsum[blockIdx.x] = lds[255];
}

__global__ void scan2_k(const int* __restrict__ bsum, int* __restrict__ boff, int nb) {
    __shared__ int lds[256];
    int t = threadIdx.x;
    lds[t] = (t < nb) ? bsum[t] : 0;
    __syncthreads();
    for (int off = 1; off < 256; off <<= 1) {
        int x = lds[t];
        int y = (t >= off) ? lds[t - off] : 0;
        __syncthreads();
        lds[t] = x + y;
        __syncthreads();
    }
    boff[t] = (t == 0) ? 0 : lds[t - 1];
}

__global__ void scan3_k(int* __restrict__ row_ptr, int* __restrict__ cursor,
                        const int* __restrict__ boff, int N, int E) {
    int i = blockIdx.x * blockDim.x + threadIdx.x;
    if (i < N) {
        int v = row_ptr[i] + boff[i >> 10];
        row_ptr[i] = v;
        cursor[i]  = v;
    }
    if (i == N) row_ptr[N] = E;
}

__global__ void fill_k(const int* __restrict__ row,
                       const int* __restrict__ col,
                       int* __restrict__ cursor, int* __restrict__ csr_row, int E) {
    int e = blockIdx.x * blockDim.x + threadIdx.x;
    if (e < E) {
        int c = col[e];
        int p = atomicAdd(&cursor[c], 1);
        __builtin_nontemporal_store(row[e], &csr_row[p]);  // scatter: bypass L2
    }
}

// all four W[k][n] f32 -> Wt[w][n][k] f16 (transposed), one launch
__global__ void wtcast4_k(const float* __restrict__ W1, const float* __restrict__ W2,
                          const float* __restrict__ W3, const float* __restrict__ W4,
                          _Float16* __restrict__ Wt) {
    int t = blockIdx.x * 256 + threadIdx.x;  // 65536
    int w = t >> 14, idx = t & 16383;
    int k = idx >> 7, n = idx & 127;
    const float* W = (w == 0) ? W1 : (w == 1) ? W2 : (w == 2) ? W3 : W4;
    Wt[(size_t)w * 16384 + n * 128 + k] = (_Float16)W[idx];
}

// ---------------- layer-1 GEMM: t1 = dis * (x @ W1), f32 in, fp16 out ----------------
// mfma_f32_16x16x32_f16: A row=l&15,k=(l>>4)*8+j ; B col=l&15 (Wt[n][k] contiguous);
// D col=l&15, row=(l>>4)*4+r.
__global__ __launch_bounds__(256) void gemm1_k(const float* __restrict__ X,
                                               const _Float16* __restrict__ Wt,
                                               const float* __restrict__ dis,
                                               _Float16* __restrict__ H, int N) {
    int wave = threadIdx.x >> 6, l = threadIdx.x & 63;
    int lr = l & 15, lk = l >> 4;
    int row0 = blockIdx.x * 128 + wave * 32;

    half8 a[2][4];
#pragma unroll
    for (int m = 0; m < 2; ++m) {
#pragma unroll
        for (int s = 0; s < 4; ++s) {
            int r = row0 + m * 16 + lr;
            int k0 = s * 32 + lk * 8;
            half8 t;
            if (r < N) {
                const float* ap = X + (size_t)r * 128 + k0;
                float4 u0 = *(const float4*)ap;
                float4 u1 = *(const float4*)(ap + 4);
                t[0] = (_Float16)u0.x; t[1] = (_Float16)u0.y;
                t[2] = (_Float16)u0.z; t[3] = (_Float16)u0.w;
                t[4] = (_Float16)u1.x; t[5] = (_Float16)u1.y;
                t[6] = (_Float16)u1.z; t[7] = (_Float16)u1.w;
            } else {
#pragma unroll
                for (int i = 0; i < 8; ++i) t[i] = (_Float16)0.0f;
            }
            a[m][s] = t;
        }
    }

    f32x4 acc[2][8];
#pragma unroll
    for (int m = 0; m < 2; ++m)
#pragma unroll
        for (int nt = 0; nt < 8; ++nt)
#pragma unroll
            for (int r = 0; r < 4; ++r) acc[m][nt][r] = 0.0f;

#pragma unroll
    for (int nt = 0; nt < 8; ++nt) {
        half8 b[4];
#pragma unroll
        for (int s = 0; s < 4; ++s)
            b[s] = *(const half8*)(Wt + (size_t)(nt * 16 + lr) * 128 + s * 32 + lk * 8);
#pragma unroll
        for (int m = 0; m < 2; ++m)
#pragma unroll
            for (int s = 0; s < 4; ++s)
                acc[m][nt] = __builtin_amdgcn_mfma_f32_16x16x32_f16(a[m][s], b[s],
                                                                    acc[m][nt], 0, 0, 0);
    }

#pragma unroll
    for (int m = 0; m < 2; ++m) {
        int   orow[4];
        float dv[4];
#pragma unroll
        for (int r = 0; r < 4; ++r) {
            orow[r] = row0 + m * 16 + lk * 4 + r;
            dv[r]   = (orow[r] < N) ? dis[orow[r]] : 0.0f;
        }
#pragma unroll
        for (int nt = 0; nt < 8; ++nt)
#pragma unroll
            for (int r = 0; r < 4; ++r)
                if (orow[r] < N)
                    H[(size_t)orow[r] * 128 + nt * 16 + lr] =
                        (_Float16)(acc[m][nt][r] * dv[r]);
    }
}

// ---------------- fused middle layer: t_l = dis * (relu(di*(sum nbr t + self) + b) @ W)
// 64 nodes/block, 4 waves; wave w gathers nodes [w*16, w*16+16) into its own LDS rows,
// then MFMAs its 16-row m-tile. No cross-wave LDS sharing -> no __syncthreads needed.
__global__ __launch_bounds__(256) void fused_k(const _Float16* __restrict__ Tin,
                                               const int* __restrict__ row_ptr,
                                               const int* __restrict__ csr_row,
                                               const float* __restrict__ dis,
                                               const float* __restrict__ bias,
                                               const _Float16* __restrict__ Wt,
                                               _Float16* __restrict__ Tout, int N) {
    __shared__ _Float16 S[64][136];  // +8 fp16 pad: row stride 272B -> 2-way banks only
    int wave = threadIdx.x >> 6, l = threadIdx.x & 63;
    int node0 = blockIdx.x * 64;
    float bx = bias[l * 2], by = bias[l * 2 + 1];
    const _Float16* hp = Tin + l * 2;

    // ---- gather phase: 16 nodes per wave, serial; lane = 2 fp16 dims ----
#pragma unroll 1
    for (int i = 0; i < 16; ++i) {
        int nl = wave * 16 + i;
        int nd = node0 + nl;
        float ox = 0.0f, oy = 0.0f;
        if (nd < N) {
            int beg = row_ptr[nd], end = row_ptr[nd + 1];
            float di = dis[nd];
            h2 self = *(const h2*)(hp + (size_t)nd * 128);
            float ax = (float)self[0], ay = (float)self[1];
            int j = beg;
            for (; j + 4 <= end; j += 4) {
                int s0 = csr_row[j],     s1 = csr_row[j + 1];
                int s2 = csr_row[j + 2], s3 = csr_row[j + 3];
                h2 v0 = *(const h2*)(hp + (size_t)s0 * 128);
                h2 v1 = *(const h2*)(hp + (size_t)s1 * 128);
                h2 v2 = *(const h2*)(hp + (size_t)s2 * 128);
                h2 v3 = *(const h2*)(hp + (size_t)s3 * 128);
                ax += (float)v0[0] + (float)v1[0] + (float)v2[0] + (float)v3[0];
                ay += (float)v0[1] + (float)v1[1] + (float)v2[1] + (float)v3[1];
            }
            for (; j < end; ++j) {
                int s = csr_row[j];
                h2 v = *(const h2*)(hp + (size_t)s * 128);
                ax += (float)v[0];
                ay += (float)v[1];
            }
            ox = fmaxf(fmaf(di, ax, bx), 0.0f);
            oy = fmaxf(fmaf(di, ay, by), 0.0f);
        }
        h2 o;
        o[0] = (_Float16)ox;
        o[1] = (_Float16)oy;
        *(h2*)&S[nl][l * 2] = o;
    }

    // ---- MFMA phase: wave's own 16 LDS rows @ Wt ----
    int lr = l & 15, lk = l >> 4;
    half8 a[4];
#pragma unroll
    for (int s = 0; s < 4; ++s)
        a[s] = *(const half8*)&S[wave * 16 + lr][s * 32 + lk * 8];

    f32x4 acc[8];
#pragma unroll
    for (int nt = 0; nt < 8; ++nt)
#pragma unroll
        for (int r = 0; r < 4; ++r) acc[nt][r] = 0.0f;

#pragma unroll
    for (int nt = 0; nt < 8; ++nt) {
        half8 b[4];
#pragma unroll
        for (int s = 0; s < 4; ++s)
            b[s] = *(const half8*)(Wt + (size_t)(nt * 16 + lr) * 128 + s * 32 + lk * 8);
#pragma unroll
        for (int s = 0; s < 4; ++s)
            acc[nt] = __builtin_amdgcn_mfma_f32_16x16x32_f16(a[s], b[s], acc[nt], 0, 0, 0);
    }

    int   orow[4];
    float dv[4];
#pragma unroll
    for (int r = 0; r < 4; ++r) {
        orow[r] = node0 + wave * 16 + lk * 4 + r;
        dv[r]   = (orow[r] < N) ? dis[orow[r]] : 0.0f;
    }
#pragma unroll
    for (int nt = 0; nt < 8; ++nt)
#pragma unroll
        for (int r = 0; r < 4; ++r)
            if (orow[r] < N)
                Tout[(size_t)orow[r] * 128 + nt * 16 + lr] =
                    (_Float16)(acc[nt][r] * dv[r]);
}

// ---------------- final layer aggregation + pooling ----------------
__global__ __launch_bounds__(256) void agg_pool_k(const _Float16* __restrict__ Hd,
                                                  const int* __restrict__ row_ptr,
                                                  const int* __restrict__ csr_row,
                                                  const float* __restrict__ dis,
                                                  const float* __restrict__ bias,
                                                  const int* __restrict__ batch,
                                                  float* __restrict__ pout, int N) {
    int wid  = (int)((blockIdx.x * (size_t)blockDim.x + threadIdx.x) >> 6);
    int lane = threadIdx.x & 63;
    if (wid >= N) return;
    int beg = row_ptr[wid], end = row_ptr[wid + 1];
    float di = dis[wid];
    const _Float16* hp = Hd + lane * 2;

    h2 self = *(const h2*)(hp + (size_t)wid * 128);
    float ax = (float)self[0], ay = (float)self[1];

    int j = beg;
    for (; j + 4 <= end; j += 4) {
        int s0 = csr_row[j], s1 = csr_row[j + 1], s2 = csr_row[j + 2], s3 = csr_row[j + 3];
        h2 v0 = *(const h2*)(hp + (size_t)s0 * 128);
        h2 v1 = *(const h2*)(hp + (size_t)s1 * 128);
        h2 v2 = *(const h2*)(hp + (size_t)s2 * 128);
        h2 v3 = *(const h2*)(hp + (size_t)s3 * 128);
        ax += (float)v0[0] + (float)v1[0] + (float)v2[0] + (float)v3[0];
        ay += (float)v0[1] + (float)v1[1] + (float)v2[1] + (float)v3[1];
    }
    for (; j < end; ++j) {
        int s = csr_row[j];
        h2 v = *(const h2*)(hp + (size_t)s * 128);
        ax += (float)v[0];
        ay += (float)v[1];
    }

    float ox = fmaxf(fmaf(di, ax, bias[lane * 2]),     0.0f);
    float oy = fmaxf(fmaf(di, ay, bias[lane * 2 + 1]), 0.0f);
    int g = batch[wid];
    atomicAdd(&pout[(size_t)g * 128 + lane * 2 + 0], ox);
    atomicAdd(&pout[(size_t)g * 128 + lane * 2 + 1], oy);
}

__global__ void fin_k(float* __restrict__ out, const unsigned int* __restrict__ cnt,
                      int total) {
    int i = blockIdx.x * blockDim.x + threadIdx.x;
    if (i < total) out[i] = out[i] / fmaxf((float)cnt[i >> 7], 1.0f);
}

// ---------------- launch ----------------
extern "C" void kernel_launch(void* const* d_in, const int* in_sizes, int n_in,
                              void* d_out, int out_size, void* d_ws, size_t ws_size,
                              hipStream_t stream) {
    const float* x  = (const float*)d_in[0];
    const float* W1 = (const float*)d_in[1]; const float* b1 = (const float*)d_in[2];
    const float* W2 = (const float*)d_in[3]; const float* b2 = (const float*)d_in[4];
    const float* W3 = (const float*)d_in[5]; const float* b3 = (const float*)d_in[6];
    const float* W4 = (const float*)d_in[7]; const float* b4 = (const float*)d_in[8];
    const int* eidx  = (const int*)d_in[9];
    const int* batch = (const int*)d_in[10];

    int N = in_sizes[0] / 128;
    int E = in_sizes[9] / 2;
    const int* erow = eidx;      // source
    const int* ecol = eidx + E;  // target

    char* ws = (char*)d_ws;
    size_t off = 0;
    auto alloc = [&](size_t bytes) -> void* {
        void* p = ws + off;
        off = (off + bytes + 255) & ~(size_t)255;
        return p;
    };
    unsigned int* deg    = (unsigned int*)alloc((size_t)N * 4);
    float*        dis    = (float*)alloc((size_t)N * 4);
    int*          rowp   = (int*)alloc((size_t)(N + 1) * 4);
    int*          cursor = (int*)alloc((size_t)N * 4);
    int*          bsum   = (int*)alloc(1024);
    int*          boff   = (int*)alloc(1024);
    unsigned int* cnt    = (unsigned int*)alloc(2048 * 4);
    int*          csr    = (int*)alloc((size_t)E * 4);
    _Float16*     Wt     = (_Float16*)alloc(4 * 128 * 128 * 2);
    _Float16*     hA     = (_Float16*)alloc((size_t)N * 128 * 2);
    _Float16*     hB     = (_Float16*)alloc((size_t)N * 128 * 2);
    (void)ws_size;

    hipMemsetAsync(deg, 0, (size_t)N * 4, stream);
    hipMemsetAsync(cnt, 0, 2048 * 4, stream);
    hipMemsetAsync(d_out, 0, (size_t)out_size * 4, stream);

    const int B = 256;
    count2_k<<<(E + B - 1) / B, B, 0, stream>>>(ecol, deg, batch, cnt, E, N);
    int nb = (N + 1023) / 1024;
    scan1_k<<<nb, 256, 0, stream>>>(deg, rowp, bsum, dis, N);
    scan2_k<<<1, 256, 0, stream>>>(bsum, boff, nb);
    scan3_k<<<(N + 1 + B - 1) / B, B, 0, stream>>>(rowp, cursor, boff, N, E);
    fill_k<<<(E + B - 1) / B, B, 0, stream>>>(erow, ecol, cursor, csr, E);
    wtcast4_k<<<256, 256, 0, stream>>>(W1, W2, W3, W4, Wt);

    int gb = (N + 127) / 128;  // gemm1 blocks
    int fb = (N + 63) / 64;    // fused blocks (64 nodes each)
    int ab = (N + 3) / 4;      // agg_pool: 4 waves/block

    gemm1_k<<<gb, 256, 0, stream>>>(x, Wt, dis, hA, N);                       // t1
    fused_k<<<fb, 256, 0, stream>>>(hA, rowp, csr, dis, b1, Wt + 16384, hB, N);  // t2
    fused_k<<<fb, 256, 0, stream>>>(hB, rowp, csr, dis, b2, Wt + 32768, hA, N);  // t3
    fused_k<<<fb, 256, 0, stream>>>(hA, rowp, csr, dis, b3, Wt + 49152, hB, N);  // t4
    agg_pool_k<<<ab, 256, 0, stream>>>(hB, rowp, csr, dis, b4, batch,
                                       (float*)d_out, N);
    fin_k<<<(out_size + B - 1) / B, B, 0, stream>>>((float*)d_out, cnt, out_size);
}